// Round 8
// baseline (944.130 us; speedup 1.0000x reference)
//
#include <hip/hip_runtime.h>
#include <math.h>

typedef _Float16 h16;
typedef _Float16 half8 __attribute__((ext_vector_type(8)));
typedef float f32x4 __attribute__((ext_vector_type(4)));

#define BATCH 16
#define CH 256
#define EPSBN 1e-5f

constexpr size_t WE_STRIDE = (size_t)CH * CH * 9;   // 589,824 elems per expert

__device__ __forceinline__ float silu_(float v) {
    return v * (1.0f / (1.0f + __expf(-v)));
}

// Implicit-GEMM 3x3 conv (pad 1) over NHWC f16 input, 9 tap-shifted GEMMs.
// ROUND-8 RESTRUCTURE (stampede theory): every prior variant synchronized all
// waves per ci-chunk (__syncthreads) -> all waves issue their loads at the
// same instant, queue behind each other (~5k cy correlated stall per tap-
// granule, structure-invariant across 7 variants), drain, and re-converge.
// Fix: NO LDS, NO barriers, 1-WAVE BLOCKS. Wave = 1 output row (64 sp) x
// 64 co, acc 4x4 frags (64 AGPR). Operands stream from global:
// per tap, pointers hoisted once; the 8 ci-chunks use compile-time immediate
// offsets (4 wf + 4 xf b128 loads + 16 MFMA per chunk). Halo rows: uniform
// tap skip (zero-pad). Halo cols: clamp addr + per-lane cndmask zero.
// 4096 independent XCD-swizzled waves desynchronize; L2 keeps w + x panels
// resident (per XCD: 2 bz x w 2.4MB + x 4MB).
// MFMA contract (m89/m91): A[m=l15][k=quad*8+j], B[k=quad*8+j][n=l15], D[m=quad*4+r][n=l15]
// MODE 0: acc[i*4+f]=mfma(xf[i],wf[f]) -> D[sp][co] -> y f16 NHWC, BN+SiLU
// MODE 1: acc[i*4+f]=mfma(wf[f],xf[i]) -> D[co][sp] -> yc f16 NCHW, BN+SiLU
template<int MODE>
__global__ __launch_bounds__(64, 3)
void conv_mfma(const h16* __restrict__ xin,
               const h16* __restrict__ wt,
               const float* __restrict__ bng, const float* __restrict__ bnb,
               const float* __restrict__ bnm, const float* __restrict__ bnv,
               const float* __restrict__ resid,
               void* __restrict__ outv)
{
    const int lane = threadIdx.x;
    const int quad = lane >> 4;
    const int l15  = lane & 15;
    // bijective XCD swizzle: 4096 blocks, 8 XCDs -> 512 consecutive swz/XCD
    // per XCD: 2 batches x 4 co-groups x 64 rows -> w,x panels L2-resident
    const int swz = (blockIdx.x & 7) * 512 + (blockIdx.x >> 3);
    const int h   = swz & 63;
    const int cog = (swz >> 6) & 3;
    const int b   = swz >> 8;
    const int co0 = cog * 64;

    f32x4 acc[16];   // acc[i*4+f]: i = sp frag, f = co frag
    #pragma unroll
    for (int i = 0; i < 16; ++i) {
        f32x4 z = {0.f, 0.f, 0.f, 0.f};
        acc[i] = z;
    }

    // lane weight base: co = co0 + f*16 + l15, ci = quad*8 (+tap, +chunk)
    const h16* wbase = wt + ((MODE == 1) ? (size_t)b * 9 * 65536 : (size_t)0)
                          + ((size_t)(co0 + l15) << 8)
                          + (size_t)(quad * 8);
    const h16* xbase = xin + ((size_t)b << 20);   // b*64*64*256

    #pragma unroll 1
    for (int tap = 0; tap < 9; ++tap) {
        const int kh = tap / 3, kw = tap - kh * 3;
        const int r  = h + kh - 1;
        if ((unsigned)r >= 64u) continue;          // zero-pad row: uniform skip

        // hoist 8 per-tap pointers; 8 ci-chunks below use imm offsets (c*64B)
        const h16* wp[4];
        #pragma unroll
        for (int f = 0; f < 4; ++f)
            wp[f] = wbase + (size_t)tap * 65536 + f * 16 * 256;

        const h16* xr = xbase + (((size_t)r << 6) << 8);   // row base (r*64*256)
        const h16* xp[4];
        int inv[4];
        #pragma unroll
        for (int i = 0; i < 4; ++i) {
            int wr_ = i * 16 + l15 + kw - 1;
            int inb = ((unsigned)wr_ < 64u);
            int wcl = inb ? wr_ : (wr_ < 0 ? 0 : 63);   // clamped addr
            inv[i] = !inb;                               // per-lane zero mask
            xp[i] = xr + wcl * 256 + quad * 8;
        }

        #pragma unroll
        for (int c = 0; c < 8; ++c) {
            half8 wf[4], xf[4];
            #pragma unroll
            for (int f = 0; f < 4; ++f)
                wf[f] = *(const half8*)(wp[f] + c * 32);
            #pragma unroll
            for (int i = 0; i < 4; ++i) {
                half8 v = *(const half8*)(xp[i] + c * 32);
                if (inv[i]) { half8 z = {0, 0, 0, 0, 0, 0, 0, 0}; v = z; }
                xf[i] = v;
            }
            if (MODE == 0) {
                #pragma unroll
                for (int i = 0; i < 4; ++i)
                    #pragma unroll
                    for (int f = 0; f < 4; ++f)
                        acc[i * 4 + f] = __builtin_amdgcn_mfma_f32_16x16x32_f16(
                            xf[i], wf[f], acc[i * 4 + f], 0, 0, 0);
            } else {
                #pragma unroll
                for (int i = 0; i < 4; ++i)
                    #pragma unroll
                    for (int f = 0; f < 4; ++f)
                        acc[i * 4 + f] = __builtin_amdgcn_mfma_f32_16x16x32_f16(
                            wf[f], xf[i], acc[i * 4 + f], 0, 0, 0);
            }
        }
    }

    if (MODE == 0) {
        // D[m=sp: i*16+quad*4+r][n=co: f*16+l15] -> y f16 NHWC, BN+SiLU
        h16* yout = (h16*)outv;
        float sc[4], sh[4];
        #pragma unroll
        for (int f = 0; f < 4; ++f) {
            int cch = co0 + f * 16 + l15;
            float s = bng[cch] * rsqrtf(bnv[cch] + EPSBN);
            sc[f] = s; sh[f] = bnb[cch] - bnm[cch] * s;
        }
        #pragma unroll
        for (int i = 0; i < 4; ++i)
            #pragma unroll
            for (int r = 0; r < 4; ++r) {
                int w = i * 16 + quad * 4 + r;
                size_t base = (((size_t)(b * 64 + h) << 6) + w) * 256
                            + co0 + l15;
                #pragma unroll
                for (int f = 0; f < 4; ++f) {
                    float v = acc[i * 4 + f][r] * sc[f] + sh[f];
                    yout[base + f * 16] = (h16)silu_(v);
                }
            }
    } else {
        // D[m=co: f*16+quad*4+r][n=sp: i*16+l15] -> yc f16 NCHW, BN+SiLU
        h16* ycp = (h16*)outv;
        #pragma unroll
        for (int f = 0; f < 4; ++f) {
            float sc[4], sh[4];
            #pragma unroll
            for (int r = 0; r < 4; ++r) {
                int cch = co0 + f * 16 + quad * 4 + r;
                float s = bng[cch] * rsqrtf(bnv[cch] + EPSBN);
                sc[r] = s; sh[r] = bnb[cch] - bnm[cch] * s;
            }
            #pragma unroll
            for (int i = 0; i < 4; ++i) {
                int w = i * 16 + l15;
                #pragma unroll
                for (int r = 0; r < 4; ++r) {
                    int cch = co0 + f * 16 + quad * 4 + r;
                    size_t idx = ((size_t)(b * CH + cch) << 12) + (h << 6) + w;
                    float v = acc[i * 4 + f][r] * sc[r] + sh[r];
                    ycp[idx] = (h16)silu_(v);
                }
            }
        }
    }
}

// out = x + yc (NCHW, 1:1 index map). Pure streaming, float4/half8 vectorized.
__global__ __launch_bounds__(256)
void finalize_kernel(const h16* __restrict__ yc, const float* __restrict__ x,
                     float* __restrict__ out) {
    const int total8 = BATCH * CH * 4096 / 8;   // 2,097,152 half8 tasks
    int i = blockIdx.x * 256 + threadIdx.x;
    const int stride = gridDim.x * 256;
    for (; i < total8; i += stride) {
        half8 v = *(const half8*)(yc + (size_t)i * 8);
        const float4* xp = (const float4*)(x + (size_t)i * 8);
        float4 a = xp[0], b = xp[1];
        float4 o0, o1;
        o0.x = a.x + (float)v[0];
        o0.y = a.y + (float)v[1];
        o0.z = a.z + (float)v[2];
        o0.w = a.w + (float)v[3];
        o1.x = b.x + (float)v[4];
        o1.y = b.y + (float)v[5];
        o1.z = b.z + (float)v[6];
        o1.w = b.w + (float)v[7];
        float4* op = (float4*)(out + (size_t)i * 8);
        op[0] = o0;
        op[1] = o1;
    }
}

// x fp32 NCHW -> xh f16 NHWC (LDS-tiled transpose). Block = (cg 64-ch group, h, b).
__global__ __launch_bounds__(256)
void prep_x(const float* __restrict__ x, h16* __restrict__ xh) {
    __shared__ float lt[64][65];
    int cg = blockIdx.x, h = blockIdx.y, b = blockIdx.z;
    int t = threadIdx.x;
    {
        int cl = t >> 2, wq = t & 3;
        const float4* src = (const float4*)(x + (((size_t)(b * CH + cg * 64 + cl)) << 12)
                                              + ((size_t)h << 6));
        #pragma unroll
        for (int k = 0; k < 4; ++k) {
            int w4 = wq + k * 4;
            float4 v = src[w4];
            lt[cl][w4 * 4 + 0] = v.x;
            lt[cl][w4 * 4 + 1] = v.y;
            lt[cl][w4 * 4 + 2] = v.z;
            lt[cl][w4 * 4 + 3] = v.w;
        }
    }
    __syncthreads();
    {
        int wl = t >> 2, cq = t & 3;
        half8 a2[2];
        h16* ap = (h16*)a2;
        #pragma unroll
        for (int m = 0; m < 16; ++m) ap[m] = (h16)lt[cq * 16 + m][wl];
        size_t base = ((((size_t)(b * 64 + h)) << 6) + wl) * 256 + cg * 64 + cq * 16;
        *(half8*)(xh + base)     = a2[0];
        *(half8*)(xh + base + 8) = a2[1];
    }
}

// w1 [co][ci][9] fp32 -> w1t [tap][co][ci] f16
__global__ void prep_w1(const float* __restrict__ w1, h16* __restrict__ w1t) {
    int pair = blockIdx.x * 256 + threadIdx.x;   // co*256+ci
    #pragma unroll
    for (int tap = 0; tap < 9; ++tap)
        w1t[((size_t)tap << 16) + pair] = (h16)w1[(size_t)pair * 9 + tap];
}

// part[slice][b][c] = partial sum over 256 sp of y NHWC (vectorized, no atomics)
__global__ __launch_bounds__(256)
void pool_kernel(const h16* __restrict__ y, float* __restrict__ part) {
    __shared__ float red[8][256];
    int slice = blockIdx.x, b = blockIdx.y;
    int t = threadIdx.x;
    int oct = t & 31, ss = t >> 5;
    float a[8];
    #pragma unroll
    for (int k = 0; k < 8; ++k) a[k] = 0.f;
    const h16* p = y + ((size_t)(b * 4096 + slice * 256 + ss)) * 256 + oct * 8;
    #pragma unroll 4
    for (int i = 0; i < 32; ++i) {
        half8 v = *(const half8*)(p + (size_t)i * 8 * 256);
        #pragma unroll
        for (int k = 0; k < 8; ++k) a[k] += (float)v[k];
    }
    #pragma unroll
    for (int k = 0; k < 8; ++k) red[ss][oct * 8 + k] = a[k];
    __syncthreads();
    float s = 0.f;
    #pragma unroll
    for (int q = 0; q < 8; ++q) s += red[q][t];
    part[((size_t)slice * BATCH + b) * 256 + t] = s;
}

__global__ void routing_kernel(const float* __restrict__ part,
                               const float* __restrict__ wr,
                               const float* __restrict__ br,
                               float* __restrict__ routing) {
    int t = threadIdx.x;
    if (t < 64) {
        int b = t >> 2, e = t & 3;
        float s = 0.f;
        for (int c = 0; c < 256; ++c) {
            float p = 0.f;
            for (int sl = 0; sl < 16; ++sl)
                p += part[((size_t)sl * BATCH + b) * 256 + c];
            s += p * wr[e * 256 + c];
        }
        s = s * (1.f / 4096.f) + br[e];
        routing[t] = 1.f / (1.f + __expf(-s));
    }
}

// wt2[b][tap][co][ci] f16 = sum_e routing[b][e] * w_e[e][(co*256+ci)*9+tap]
__global__ __launch_bounds__(256)
void kern_gen(const float* __restrict__ w_e,
              const float* __restrict__ routing,
              h16* __restrict__ wt2) {
    __shared__ float lw[4 * 2304];   // 36,864 B
    __shared__ float rsh[64];
    int t = threadIdx.x;
    int pair0 = blockIdx.x * 256;
    if (t < 64) rsh[t] = routing[t];
    #pragma unroll
    for (int e = 0; e < 4; ++e) {
        const float4* src = (const float4*)(w_e + (size_t)e * WE_STRIDE + (size_t)pair0 * 9);
        #pragma unroll
        for (int k = 0; k < 3; ++k) {
            int idx = t + k * 256;
            if (idx < 576) {
                float4 v = src[idx];
                float* d = &lw[e * 2304 + idx * 4];
                d[0] = v.x; d[1] = v.y; d[2] = v.z; d[3] = v.w;
            }
        }
    }
    __syncthreads();
    float wv[4][9];
    #pragma unroll
    for (int e = 0; e < 4; ++e)
        #pragma unroll
        for (int k = 0; k < 9; ++k)
            wv[e][k] = lw[e * 2304 + t * 9 + k];
    for (int b = 0; b < 16; ++b) {
        float r0 = rsh[b * 4 + 0], r1 = rsh[b * 4 + 1];
        float r2 = rsh[b * 4 + 2], r3 = rsh[b * 4 + 3];
        #pragma unroll
        for (int tap = 0; tap < 9; ++tap) {
            float s = r0 * wv[0][tap] + r1 * wv[1][tap]
                    + r2 * wv[2][tap] + r3 * wv[3][tap];
            wt2[((size_t)(b * 9 + tap) << 16) + pair0 + t] = (h16)s;
        }
    }
}

extern "C" void kernel_launch(void* const* d_in, const int* in_sizes, int n_in,
                              void* d_out, int out_size, void* d_ws, size_t ws_size,
                              hipStream_t stream) {
    const float* x    = (const float*)d_in[0];
    const float* w1   = (const float*)d_in[1];
    const float* bn1g = (const float*)d_in[2];
    const float* bn1b = (const float*)d_in[3];
    const float* bn1m = (const float*)d_in[4];
    const float* bn1v = (const float*)d_in[5];
    const float* wr   = (const float*)d_in[6];
    const float* br   = (const float*)d_in[7];
    const float* w_e  = (const float*)d_in[8];
    const float* bn2g = (const float*)d_in[9];
    const float* bn2b = (const float*)d_in[10];
    const float* bn2m = (const float*)d_in[11];
    const float* bn2v = (const float*)d_in[12];

    char* w = (char*)d_ws;
    h16*   xh      = (h16*)(w);                   // 33,554,432 B (x f16 NHWC; reused as yc f16 NCHW)
    h16*   y       = (h16*)(w + 33554432);        // 33,554,432 B (f16 NHWC)
    h16*   w1t     = (h16*)(w + 67108864);        //  1,179,648 B
    h16*   wt2     = (h16*)(w + 68288512);        // 18,874,368 B
    float* part    = (float*)(w + 87162880);      //    262,144 B
    float* routing = (float*)(w + 87425024);      //        256 B

    prep_x<<<dim3(4, 64, BATCH), 256, 0, stream>>>(x, xh);
    prep_w1<<<dim3(256), 256, 0, stream>>>(w1, w1t);

    dim3 cgrid(4096);   // 1-wave blocks: 64 rows x 4 co-groups x 16 bz, swizzled
    conv_mfma<0><<<cgrid, 64, 0, stream>>>(xh, w1t, bn1g, bn1b, bn1m, bn1v,
                                           nullptr, y);
    pool_kernel<<<dim3(16, BATCH), 256, 0, stream>>>(y, part);
    routing_kernel<<<dim3(1), 64, 0, stream>>>(part, wr, br, routing);
    kern_gen<<<dim3(256), 256, 0, stream>>>(w_e, routing, wt2);
    h16* yc = xh;   // xh dead after conv<0>
    conv_mfma<1><<<cgrid, 64, 0, stream>>>(y, wt2, bn2g, bn2b, bn2m, bn2v,
                                           nullptr, yc);
    finalize_kernel<<<dim3(2048), 256, 0, stream>>>(yc, x, (float*)d_out);
}